// Round 7
// baseline (118.361 us; speedup 1.0000x reference)
//
#include <hip/hip_runtime.h>
#include <hip/hip_bf16.h>
#include <math.h>

#define BB 32
#define TT 2048
#define FF 512
#define UU 512

typedef __attribute__((ext_vector_type(4))) float f32x4;
typedef __attribute__((ext_vector_type(4))) short bf16x4;
typedef __attribute__((ext_vector_type(8))) short bf16x8;

__device__ inline short f2bf(float f) {
  union { __hip_bfloat16 h; short s; } u;
  u.h = __float2bfloat16(f);
  return u.s;
}

// tanh(x) = 1 - 2/(exp(2x)+1). ~6 VALU ops, ~1e-6 abs err, saturates right.
__device__ inline float tanh_fast(float x) {
  float e = __expf(2.0f * x);
  return 1.0f - 2.0f * __builtin_amdgcn_rcpf(e + 1.0f);
}

// ws layout (floats):
// hw:      [0,      16384)
// mbuf:    [16384,  18432)   32 b x 64 tiles
// lbuf:    [18432,  20480)
// cpart:   shorts at float-offset 20480: 32b x 64t x 512f bf16 -> [20480, 544768)
// c:       [544768, 561152)  direct write by k6
// G:       [561152, 610304)  atomic target, zeroed up front
// qbuf:    [610304, 626688)  atomic target, zeroed up front
// zs:      [626688, 643072)
// rh:      [643072, 659456)
// Up:      shorts at float-offset 659456 (262144 shorts = 512 KB)

__global__ __launch_bounds__(256) void k1_hw(
    const float* __restrict__ h, const float* __restrict__ Wa,
    const float* __restrict__ Wa_bias, const float* __restrict__ Ua_bias,
    float* __restrict__ hw) {
  int idx = blockIdx.x * blockDim.x + threadIdx.x;  // 16384 = B*U
  int b = idx >> 9;
  int u = idx & 511;
  float acc = Wa_bias[u] + Ua_bias[u];
  const float* hrow = h + b * UU;
  for (int f = 0; f < FF; ++f) acc += hrow[f] * Wa[f * UU + u];
  hw[idx] = acc;
}

// Pack Ua (fp32 [k][n]) into fragment-native bf16 layout.
__global__ __launch_bounds__(64) void k0_pack(
    const float* __restrict__ Ua, short* __restrict__ Up) {
  const int n16 = blockIdx.x;   // 0..31
  const int k32 = blockIdx.y;   // 0..15
  const int l = threadIdx.x;    // 0..63
  const int n = n16 * 16 + (l & 15);
  const int g = l >> 4;
  bf16x8 v;
#pragma unroll
  for (int i = 0; i < 8; ++i) {
    int k = k32 * 32 + (i < 4 ? g * 4 + i : 16 + g * 4 + (i - 4));
    v[i] = f2bf(Ua[k * UU + n]);
  }
  *reinterpret_cast<bf16x8*>(Up + ((size_t)(n16 * 16 + k32) * 64 + l) * 8) = v;
}

// Flash kernel v3: t-tile = 32, 512 threads (8 waves), LDS ~34 KB ->
// 4 blocks/CU = 32 waves/CU. Wave w owns u-slice [64w, 64w+64): mf 0..1,
// nf 0..3. acc = 32 VGPR.
__global__ __launch_bounds__(512, 8) void k2_flash(
    const float* __restrict__ ann, const short* __restrict__ Up,
    const float* __restrict__ Va, const float* __restrict__ hw,
    float* __restrict__ mbuf, float* __restrict__ lbuf,
    short* __restrict__ cpart) {
  __shared__ short Af[16384];      // 32 fb x 64 lane x 8 bf16 = 32 KB
  __shared__ float red[8][32];
  __shared__ float e_all[32];
  const int tile = blockIdx.x;     // 0..63
  const int b = blockIdx.y;
  const int t0 = tile * 32;
  const int tid = threadIdx.x;
  const int w = tid >> 6;          // wave 0..7
  const int l = tid & 63;
  const int lo = l & 15;
  const int g = l >> 4;

  const float* annb = ann + ((size_t)b * TT + t0) * FF;

  // ---- stage: 2048 fragment entries, 4 per thread ----
#pragma unroll
  for (int v = 0; v < 4; ++v) {
    const int E = v * 512 + tid;        // entry = (mf*16 + k32)*64 + slot
    const int mf = E >> 10;
    const int k32 = (E >> 6) & 15;
    const int slot = E & 63;
    const int row = mf * 16 + (slot & 15);
    const int gq = slot >> 4;
    const float* src = annb + (size_t)row * FF + k32 * 32 + gq * 4;
    f32x4 a0 = *reinterpret_cast<const f32x4*>(src);
    f32x4 a1 = *reinterpret_cast<const f32x4*>(src + 16);
    bf16x8 o;
    o[0] = f2bf(a0.x); o[1] = f2bf(a0.y); o[2] = f2bf(a0.z); o[3] = f2bf(a0.w);
    o[4] = f2bf(a1.x); o[5] = f2bf(a1.y); o[6] = f2bf(a1.z); o[7] = f2bf(a1.w);
    *reinterpret_cast<bf16x8*>(&Af[E * 8]) = o;
  }
  __syncthreads();

  // ---- MFMA: 2 mf x 4 nf, k32 = 0..15, Up double-buffered prefetch ----
  f32x4 acc[2][4];
#pragma unroll
  for (int mf = 0; mf < 2; ++mf)
#pragma unroll
    for (int nf = 0; nf < 4; ++nf) acc[mf][nf] = (f32x4)0.f;

  bf16x8 bA[4], bB[4];
#pragma unroll
  for (int nf = 0; nf < 4; ++nf)
    bA[nf] = *reinterpret_cast<const bf16x8*>(
        Up + ((size_t)((w * 4 + nf) * 16 + 0) * 64 + l) * 8);

#pragma unroll
  for (int kk = 0; kk < 8; ++kk) {
    const int k0 = 2 * kk;
#pragma unroll
    for (int nf = 0; nf < 4; ++nf)
      bB[nf] = *reinterpret_cast<const bf16x8*>(
          Up + ((size_t)((w * 4 + nf) * 16 + k0 + 1) * 64 + l) * 8);
#pragma unroll
    for (int mf = 0; mf < 2; ++mf) {
      bf16x8 af = *reinterpret_cast<const bf16x8*>(
          &Af[((mf * 16 + k0) * 64 + l) * 8]);
#pragma unroll
      for (int nf = 0; nf < 4; ++nf)
        acc[mf][nf] = __builtin_amdgcn_mfma_f32_16x16x32_bf16(
            af, bA[nf], acc[mf][nf], 0, 0, 0);
    }
    if (kk < 7) {
#pragma unroll
      for (int nf = 0; nf < 4; ++nf)
        bA[nf] = *reinterpret_cast<const bf16x8*>(
            Up + ((size_t)((w * 4 + nf) * 16 + k0 + 2) * 64 + l) * 8);
    }
#pragma unroll
    for (int mf = 0; mf < 2; ++mf) {
      bf16x8 af = *reinterpret_cast<const bf16x8*>(
          &Af[((mf * 16 + k0 + 1) * 64 + l) * 8]);
#pragma unroll
      for (int nf = 0; nf < 4; ++nf)
        acc[mf][nf] = __builtin_amdgcn_mfma_f32_16x16x32_bf16(
            af, bB[nf], acc[mf][nf], 0, 0, 0);
    }
  }

  // ---- scores epilogue: tanh(acc + hw[u]) * Va[u], reduce over u ----
  const float* hwb = hw + b * UU;
  float part[2][4];
#pragma unroll
  for (int mf = 0; mf < 2; ++mf)
#pragma unroll
    for (int r = 0; r < 4; ++r) part[mf][r] = 0.f;
#pragma unroll
  for (int nf = 0; nf < 4; ++nf) {
    const int u = w * 64 + nf * 16 + lo;
    const float hv = hwb[u];
    const float vv = Va[u];
#pragma unroll
    for (int mf = 0; mf < 2; ++mf)
#pragma unroll
      for (int r = 0; r < 4; ++r)
        part[mf][r] += tanh_fast(acc[mf][nf][r] + hv) * vv;
  }
#pragma unroll
  for (int mf = 0; mf < 2; ++mf)
#pragma unroll
    for (int r = 0; r < 4; ++r) {
      float s = part[mf][r];
      s += __shfl_xor(s, 1);
      s += __shfl_xor(s, 2);
      s += __shfl_xor(s, 4);
      s += __shfl_xor(s, 8);
      part[mf][r] = s;
    }
  if (lo == 0) {
#pragma unroll
    for (int mf = 0; mf < 2; ++mf)
#pragma unroll
      for (int r = 0; r < 4; ++r)
        red[w][mf * 16 + g * 4 + r] = part[mf][r];
  }
  __syncthreads();

  // ---- tile softmax stats (first 32 threads): m, e_t, l ----
  if (tid < 32) {
    float s = red[0][tid] + red[1][tid] + red[2][tid] + red[3][tid] +
              red[4][tid] + red[5][tid] + red[6][tid] + red[7][tid];
    float m = s;
#pragma unroll
    for (int off = 1; off < 32; off <<= 1) m = fmaxf(m, __shfl_xor(m, off));
    float e = __expf(s - m);
    float ls = e;
#pragma unroll
    for (int off = 1; off < 32; off <<= 1) ls += __shfl_xor(ls, off);
    e_all[tid] = e;
    if (tid == 0) {
      mbuf[b * 64 + tile] = m;
      lbuf[b * 64 + tile] = ls;
    }
  }
  __syncthreads();

  // ---- partial context: thread owns col f = tid; lane-staggered t ----
  {
    const int f = tid;               // 0..511
    const int kk2 = f >> 5;          // k32
    const int q = (f >> 2) & 3;      // g
    const int ib = (f & 3) + 4 * ((f >> 4) & 1);
    float a = 0.f;
    for (int it = 0; it < 32; ++it) {
      const int t = (it + tid) & 31;
      const int idx = (((t >> 4) * 16 + kk2) * 64 + q * 16 + (t & 15)) * 8 + ib;
      unsigned short vv = *reinterpret_cast<const unsigned short*>(&Af[idx]);
      a += e_all[t] * __uint_as_float(((unsigned)vv) << 16);
    }
    cpart[(size_t)(b * 64 + tile) * 512 + f] = f2bf(a);
  }
}

// Combine tile partials (bf16): c[b][f] = sum_i w_i*cpart_i[f] / sum_i w_i*l_i.
__global__ __launch_bounds__(256) void k6_combine(
    const float* __restrict__ mbuf, const float* __restrict__ lbuf,
    const short* __restrict__ cpart, float* __restrict__ c) {
  const int b = blockIdx.x;
  const int tid = threadIdx.x;
  __shared__ float sm[64], sl[64], sw[64];
  if (tid < 64) {
    sm[tid] = mbuf[b * 64 + tid];
    sl[tid] = lbuf[b * 64 + tid];
  }
  __syncthreads();
  float M = -1e30f;
#pragma unroll
  for (int i = 0; i < 64; ++i) M = fmaxf(M, sm[i]);
  if (tid < 64) sw[tid] = __expf(sm[tid] - M);
  __syncthreads();
  float D = 0.f;
#pragma unroll
  for (int i = 0; i < 64; ++i) D += sw[i] * sl[i];
  const float inv = 1.f / D;
  const int f = tid * 2;
  float a0 = 0.f, a1 = 0.f;
  for (int i = 0; i < 64; ++i) {
    const unsigned vv = *reinterpret_cast<const unsigned*>(
        &cpart[(size_t)(b * 64 + i) * 512 + f]);
    const float wi = sw[i];
    a0 += wi * __uint_as_float(vv << 16);
    a1 += wi * __uint_as_float(vv & 0xffff0000u);
  }
  c[b * FF + f]     = a0 * inv;
  c[b * FF + f + 1] = a1 * inv;
}

// --- gate GEMMs, LDS-tiled, split-K x8 ------------------------------------
__global__ __launch_bounds__(512) void k5a_gates(
    const float* __restrict__ x, const float* __restrict__ cc,
    const float* __restrict__ h, const float* __restrict__ kern,
    const float* __restrict__ ak, const float* __restrict__ rk,
    float* __restrict__ G) {
  __shared__ float wsx[64][64], wsa[64][64], wsr[64][64];
  __shared__ float xs[32][64], cs[32][64], hs[32][64];
  const int n0 = blockIdx.x * 64;
  const int kg0 = blockIdx.y * 64;
  const bool has_r = (n0 < 1024);
  const int tid = threadIdx.x;
  const int n = tid & 63;
  const int b0 = (tid >> 6) * 4;
  const int wrow = tid >> 3, wcol = (tid & 7) * 8;
  const int orow = tid >> 4, ocol = (tid & 15) * 4;
  float acc[4] = {0.f, 0.f, 0.f, 0.f};

  {
    const size_t wb = (size_t)(kg0 + wrow) * 1536 + n0 + wcol;
    *reinterpret_cast<float4*>(&wsx[wrow][wcol])     = *reinterpret_cast<const float4*>(kern + wb);
    *reinterpret_cast<float4*>(&wsx[wrow][wcol + 4]) = *reinterpret_cast<const float4*>(kern + wb + 4);
    *reinterpret_cast<float4*>(&wsa[wrow][wcol])     = *reinterpret_cast<const float4*>(ak + wb);
    *reinterpret_cast<float4*>(&wsa[wrow][wcol + 4]) = *reinterpret_cast<const float4*>(ak + wb + 4);
    if (has_r) {
      *reinterpret_cast<float4*>(&wsr[wrow][wcol])     = *reinterpret_cast<const float4*>(rk + wb);
      *reinterpret_cast<float4*>(&wsr[wrow][wcol + 4]) = *reinterpret_cast<const float4*>(rk + wb + 4);
    }
    *reinterpret_cast<float4*>(&xs[orow][ocol]) =
        *reinterpret_cast<const float4*>(x + orow * FF + kg0 + ocol);
    *reinterpret_cast<float4*>(&cs[orow][ocol]) =
        *reinterpret_cast<const float4*>(cc + orow * FF + kg0 + ocol);
    *reinterpret_cast<float4*>(&hs[orow][ocol]) =
        *reinterpret_cast<const float4*>(h + orow * UU + kg0 + ocol);
  }
  __syncthreads();
  if (has_r) {
#pragma unroll 8
    for (int k = 0; k < 64; ++k) {
      const float wx = wsx[k][n], wa = wsa[k][n], wr = wsr[k][n];
#pragma unroll
      for (int j = 0; j < 4; ++j)
        acc[j] += xs[b0 + j][k] * wx + cs[b0 + j][k] * wa + hs[b0 + j][k] * wr;
    }
  } else {
#pragma unroll 8
    for (int k = 0; k < 64; ++k) {
      const float wx = wsx[k][n], wa = wsa[k][n];
#pragma unroll
      for (int j = 0; j < 4; ++j)
        acc[j] += xs[b0 + j][k] * wx + cs[b0 + j][k] * wa;
    }
  }
#pragma unroll
  for (int j = 0; j < 4; ++j)
    atomicAdd(&G[(size_t)(b0 + j) * 1536 + n0 + n], acc[j]);
}

__global__ __launch_bounds__(256) void k5b_zr(
    const float* __restrict__ G, const float* __restrict__ h,
    const float* __restrict__ bias, const float* __restrict__ abias,
    float* __restrict__ zs, float* __restrict__ rh) {
  int idx = blockIdx.x * blockDim.x + threadIdx.x;  // 16384
  int b = idx >> 9;
  int u = idx & 511;
  float z = 0.2f * (G[(size_t)b * 1536 + u] + bias[u] + abias[u]) + 0.5f;
  z = fminf(fmaxf(z, 0.f), 1.f);
  float r = 0.2f * (G[(size_t)b * 1536 + 512 + u] + bias[512 + u] + abias[512 + u]) + 0.5f;
  r = fminf(fmaxf(r, 0.f), 1.f);
  zs[idx] = z;
  rh[idx] = r * h[idx];
}

__global__ __launch_bounds__(512) void k5c_q(
    const float* __restrict__ rh, const float* __restrict__ rk,
    float* __restrict__ qbuf) {
  __shared__ float wsr[64][64];
  __shared__ float rs[32][64];
  const int n0 = blockIdx.x * 64;
  const int kg0 = blockIdx.y * 64;
  const int tid = threadIdx.x;
  const int n = tid & 63;
  const int b0 = (tid >> 6) * 4;
  const int wrow = tid >> 3, wcol = (tid & 7) * 8;
  const int orow = tid >> 4, ocol = (tid & 15) * 4;
  float acc[4] = {0.f, 0.f, 0.f, 0.f};

  {
    const size_t wb = (size_t)(kg0 + wrow) * 1536 + 1024 + n0 + wcol;
    *reinterpret_cast<float4*>(&wsr[wrow][wcol])     = *reinterpret_cast<const float4*>(rk + wb);
    *reinterpret_cast<float4*>(&wsr[wrow][wcol + 4]) = *reinterpret_cast<const float4*>(rk + wb + 4);
    *reinterpret_cast<float4*>(&rs[orow][ocol]) =
        *reinterpret_cast<const float4*>(rh + orow * UU + kg0 + ocol);
  }
  __syncthreads();
#pragma unroll 8
  for (int k = 0; k < 64; ++k) {
    const float w = wsr[k][n];
#pragma unroll
    for (int j = 0; j < 4; ++j) acc[j] += rs[b0 + j][k] * w;
  }
#pragma unroll
  for (int j = 0; j < 4; ++j)
    atomicAdd(&qbuf[(b0 + j) * UU + n0 + n], acc[j]);
}

__global__ __launch_bounds__(256) void k5d_out(
    const float* __restrict__ G, const float* __restrict__ qbuf,
    const float* __restrict__ zs, const float* __restrict__ h,
    const float* __restrict__ bias, const float* __restrict__ abias,
    float* __restrict__ out) {
  int idx = blockIdx.x * blockDim.x + threadIdx.x;  // 16384
  int b = idx >> 9;
  int u = idx & 511;
  float hh = tanhf(G[(size_t)b * 1536 + 1024 + u] + bias[1024 + u] +
                   abias[1024 + u] + qbuf[idx]);
  float z = zs[idx];
  out[idx] = z * h[idx] + (1.f - z) * hh;
}

extern "C" void kernel_launch(void* const* d_in, const int* in_sizes, int n_in,
                              void* d_out, int out_size, void* d_ws, size_t ws_size,
                              hipStream_t stream) {
  const float* x       = (const float*)d_in[0];
  const float* h       = (const float*)d_in[1];
  const float* ann     = (const float*)d_in[2];
  const float* kern    = (const float*)d_in[3];
  const float* rk      = (const float*)d_in[4];
  const float* ak      = (const float*)d_in[5];
  const float* Wa      = (const float*)d_in[6];
  const float* Ua      = (const float*)d_in[7];
  const float* Va      = (const float*)d_in[8];
  const float* bias    = (const float*)d_in[9];
  const float* abias   = (const float*)d_in[10];
  const float* Wa_bias = (const float*)d_in[11];
  const float* Ua_bias = (const float*)d_in[12];

  float* ws      = (float*)d_ws;
  float* hw      = ws;            // 16384
  float* mbuf    = ws + 16384;    // 2048
  float* lbuf    = ws + 18432;    // 2048
  short* cpart_h = (short*)(ws + 20480);  // 1048576 shorts (2 MB)
  float* c       = ws + 544768;   // 16384
  float* G       = ws + 561152;   // 49152
  float* qbuf    = ws + 610304;   // 16384
  float* zs      = ws + 626688;   // 16384
  float* rh      = ws + 643072;   // 16384
  short* Up      = (short*)(ws + 659456);  // 262144 shorts

  // zero atomic targets G + qbuf (contiguous 65536 floats)
  hipMemsetAsync(G, 0, 65536 * sizeof(float), stream);

  dim3 g0(32, 16);
  k0_pack<<<g0, 64, 0, stream>>>(Ua, Up);

  k1_hw<<<64, 256, 0, stream>>>(h, Wa, Wa_bias, Ua_bias, hw);

  dim3 g2(TT / 32, BB);
  k2_flash<<<g2, 512, 0, stream>>>(ann, Up, Va, hw, mbuf, lbuf, cpart_h);

  k6_combine<<<BB, 256, 0, stream>>>(mbuf, lbuf, cpart_h, c);

  dim3 g5a(24, 8);
  k5a_gates<<<g5a, 512, 0, stream>>>(x, c, h, kern, ak, rk, G);

  k5b_zr<<<64, 256, 0, stream>>>(G, h, bias, abias, zs, rh);

  dim3 g5c(8, 8);
  k5c_q<<<g5c, 512, 0, stream>>>(rh, rk, qbuf);

  k5d_out<<<64, 256, 0, stream>>>(G, qbuf, zs, h, bias, abias, (float*)d_out);
}

// Round 8
// 110.063 us; speedup vs baseline: 1.0754x; 1.0754x over previous
//
#include <hip/hip_runtime.h>
#include <hip/hip_bf16.h>
#include <math.h>

#define BB 32
#define TT 2048
#define FF 512
#define UU 512

typedef __attribute__((ext_vector_type(4))) float f32x4;
typedef __attribute__((ext_vector_type(4))) short bf16x4;
typedef __attribute__((ext_vector_type(8))) short bf16x8;

__device__ inline short f2bf(float f) {
  union { __hip_bfloat16 h; short s; } u;
  u.h = __float2bfloat16(f);
  return u.s;
}

// tanh(x) = 1 - 2/(exp(2x)+1). ~6 VALU ops, ~1e-6 abs err, saturates right.
__device__ inline float tanh_fast(float x) {
  float e = __expf(2.0f * x);
  return 1.0f - 2.0f * __builtin_amdgcn_rcpf(e + 1.0f);
}

// ws layout (floats):
// hw:     [0,      16384)
// mbuf:   [16384,  17408)    32 b x 32 tiles
// lbuf:   [17408,  18432)
// cpart:  [18432,  542720)   32 b x 32 tiles x 512 f (f32)
// c:      [542720, 559104)   direct write by k6
// G:      [559104, 608256)   atomic target, zeroed up front
// qbuf:   [608256, 624640)   atomic target, zeroed up front
// zs:     [624640, 641024)
// rh:     [641024, 657408)
// Up:     shorts at float-offset 657408 (262144 shorts = 512 KB)

__global__ __launch_bounds__(256) void k1_hw(
    const float* __restrict__ h, const float* __restrict__ Wa,
    const float* __restrict__ Wa_bias, const float* __restrict__ Ua_bias,
    float* __restrict__ hw) {
  int idx = blockIdx.x * blockDim.x + threadIdx.x;  // 16384 = B*U
  int b = idx >> 9;
  int u = idx & 511;
  float acc = Wa_bias[u] + Ua_bias[u];
  const float* hrow = h + b * UU;
  for (int f = 0; f < FF; ++f) acc += hrow[f] * Wa[f * UU + u];
  hw[idx] = acc;
}

// Pack Ua (fp32 [k][n]) into fragment-native bf16 layout.
__global__ __launch_bounds__(64) void k0_pack(
    const float* __restrict__ Ua, short* __restrict__ Up) {
  const int n16 = blockIdx.x;   // 0..31
  const int k32 = blockIdx.y;   // 0..15
  const int l = threadIdx.x;    // 0..63
  const int n = n16 * 16 + (l & 15);
  const int g = l >> 4;
  bf16x8 v;
#pragma unroll
  for (int i = 0; i < 8; ++i) {
    int k = k32 * 32 + (i < 4 ? g * 4 + i : 16 + g * 4 + (i - 4));
    v[i] = f2bf(Ua[k * UU + n]);
  }
  *reinterpret_cast<bf16x8*>(Up + ((size_t)(n16 * 16 + k32) * 64 + l) * 8) = v;
}

// Flash kernel v4: t-tile = 64, 1024 threads (16 waves), LDS ~72 KB ->
// 2 blocks/CU = 32 waves/CU. Wave w owns u-slice [32w, 32w+32): mf 0..3,
// nf 0..1. acc = 32 VGPR. Up traffic: 512 KB/block x 1024 blocks = 512 MB.
__global__ __launch_bounds__(1024, 8) void k2_flash(
    const float* __restrict__ ann, const short* __restrict__ Up,
    const float* __restrict__ Va, const float* __restrict__ hw,
    float* __restrict__ mbuf, float* __restrict__ lbuf,
    float* __restrict__ cpart) {
  __shared__ short Af[32768];      // 64 fb x 64 lane x 8 bf16 = 64 KB
  __shared__ float red[16][64];    // 4 KB
  __shared__ float e_all[64];
  __shared__ float ctx[2][512];    // 4 KB
  const int tile = blockIdx.x;     // 0..31
  const int b = blockIdx.y;
  const int t0 = tile * 64;
  const int tid = threadIdx.x;     // 0..1023
  const int w = tid >> 6;          // wave 0..15
  const int l = tid & 63;
  const int lo = l & 15;
  const int g = l >> 4;

  const float* annb = ann + ((size_t)b * TT + t0) * FF;

  // ---- initial B prefetch (before staging barrier, hides L2 latency) ----
  bf16x8 bA[2], bB[2];
#pragma unroll
  for (int nf = 0; nf < 2; ++nf)
    bA[nf] = *reinterpret_cast<const bf16x8*>(
        Up + ((size_t)((w * 2 + nf) * 16 + 0) * 64 + l) * 8);

  // ---- stage: 4096 fragment entries, 4 per thread ----
#pragma unroll
  for (int v = 0; v < 4; ++v) {
    const int E = v * 1024 + tid;       // entry = (mf*16 + k32)*64 + slot
    const int mf = E >> 10;
    const int k32 = (E >> 6) & 15;
    const int slot = E & 63;
    const int row = mf * 16 + (slot & 15);
    const int gq = slot >> 4;
    const float* src = annb + (size_t)row * FF + k32 * 32 + gq * 4;
    f32x4 a0 = *reinterpret_cast<const f32x4*>(src);
    f32x4 a1 = *reinterpret_cast<const f32x4*>(src + 16);
    bf16x8 o;
    o[0] = f2bf(a0.x); o[1] = f2bf(a0.y); o[2] = f2bf(a0.z); o[3] = f2bf(a0.w);
    o[4] = f2bf(a1.x); o[5] = f2bf(a1.y); o[6] = f2bf(a1.z); o[7] = f2bf(a1.w);
    *reinterpret_cast<bf16x8*>(&Af[E * 8]) = o;
  }
  __syncthreads();

  // ---- MFMA: 4 mf x 2 nf, k32 = 0..15, Up double-buffered prefetch ----
  f32x4 acc[4][2];
#pragma unroll
  for (int mf = 0; mf < 4; ++mf)
#pragma unroll
    for (int nf = 0; nf < 2; ++nf) acc[mf][nf] = (f32x4)0.f;

#pragma unroll
  for (int kk = 0; kk < 8; ++kk) {
    const int k0 = 2 * kk;
#pragma unroll
    for (int nf = 0; nf < 2; ++nf)
      bB[nf] = *reinterpret_cast<const bf16x8*>(
          Up + ((size_t)((w * 2 + nf) * 16 + k0 + 1) * 64 + l) * 8);
#pragma unroll
    for (int mf = 0; mf < 4; ++mf) {
      bf16x8 af = *reinterpret_cast<const bf16x8*>(
          &Af[((mf * 16 + k0) * 64 + l) * 8]);
#pragma unroll
      for (int nf = 0; nf < 2; ++nf)
        acc[mf][nf] = __builtin_amdgcn_mfma_f32_16x16x32_bf16(
            af, bA[nf], acc[mf][nf], 0, 0, 0);
    }
    if (kk < 7) {
#pragma unroll
      for (int nf = 0; nf < 2; ++nf)
        bA[nf] = *reinterpret_cast<const bf16x8*>(
            Up + ((size_t)((w * 2 + nf) * 16 + k0 + 2) * 64 + l) * 8);
    }
#pragma unroll
    for (int mf = 0; mf < 4; ++mf) {
      bf16x8 af = *reinterpret_cast<const bf16x8*>(
          &Af[((mf * 16 + k0 + 1) * 64 + l) * 8]);
#pragma unroll
      for (int nf = 0; nf < 2; ++nf)
        acc[mf][nf] = __builtin_amdgcn_mfma_f32_16x16x32_bf16(
            af, bB[nf], acc[mf][nf], 0, 0, 0);
    }
  }

  // ---- scores epilogue: tanh(acc + hw[u]) * Va[u], reduce over u ----
  const float* hwb = hw + b * UU;
  float part[4][4];
#pragma unroll
  for (int mf = 0; mf < 4; ++mf)
#pragma unroll
    for (int r = 0; r < 4; ++r) part[mf][r] = 0.f;
#pragma unroll
  for (int nf = 0; nf < 2; ++nf) {
    const int u = w * 32 + nf * 16 + lo;
    const float hv = hwb[u];
    const float vv = Va[u];
#pragma unroll
    for (int mf = 0; mf < 4; ++mf)
#pragma unroll
      for (int r = 0; r < 4; ++r)
        part[mf][r] += tanh_fast(acc[mf][nf][r] + hv) * vv;
  }
#pragma unroll
  for (int mf = 0; mf < 4; ++mf)
#pragma unroll
    for (int r = 0; r < 4; ++r) {
      float s = part[mf][r];
      s += __shfl_xor(s, 1);
      s += __shfl_xor(s, 2);
      s += __shfl_xor(s, 4);
      s += __shfl_xor(s, 8);
      part[mf][r] = s;
    }
  if (lo == 0) {
#pragma unroll
    for (int mf = 0; mf < 4; ++mf)
#pragma unroll
      for (int r = 0; r < 4; ++r)
        red[w][mf * 16 + g * 4 + r] = part[mf][r];
  }
  __syncthreads();

  // ---- tile softmax stats (first 64 threads): m, e_t, l ----
  if (tid < 64) {
    float s = 0.f;
#pragma unroll
    for (int ww = 0; ww < 16; ++ww) s += red[ww][tid];
    float m = s;
#pragma unroll
    for (int off = 1; off < 64; off <<= 1) m = fmaxf(m, __shfl_xor(m, off));
    float e = __expf(s - m);
    float ls = e;
#pragma unroll
    for (int off = 1; off < 64; off <<= 1) ls += __shfl_xor(ls, off);
    e_all[tid] = e;
    if (tid == 0) {
      mbuf[b * 32 + tile] = m;
      lbuf[b * 32 + tile] = ls;
    }
  }
  __syncthreads();

  // ---- partial context: col f = tid&511, t-half = tid>>9 ----
  {
    const int f = tid & 511;
    const int th = tid >> 9;         // 0 or 1 -> t in [32*th, 32*th+32)
    const int kk2 = f >> 5;          // k32
    const int q = (f >> 2) & 3;      // g
    const int ib = (f & 3) + 4 * ((f >> 4) & 1);
    float a = 0.f;
    for (int it = 0; it < 32; ++it) {
      const int t = th * 32 + ((it + tid) & 31);
      const int idx = (((t >> 4) * 16 + kk2) * 64 + q * 16 + (t & 15)) * 8 + ib;
      unsigned short vv = *reinterpret_cast<const unsigned short*>(&Af[idx]);
      a += e_all[t] * __uint_as_float(((unsigned)vv) << 16);
    }
    ctx[th][f] = a;
  }
  __syncthreads();
  if (tid < 512)
    cpart[(size_t)(b * 32 + tile) * 512 + tid] = ctx[0][tid] + ctx[1][tid];
}

// Combine tile partials: c[b][f] = sum_i w_i*cpart_i[f] / sum_i w_i*l_i.
__global__ __launch_bounds__(256) void k6_combine(
    const float* __restrict__ mbuf, const float* __restrict__ lbuf,
    const float* __restrict__ cpart, float* __restrict__ c) {
  const int b = blockIdx.x;
  const int tid = threadIdx.x;
  __shared__ float sm[32], sl[32];
  if (tid < 32) {
    sm[tid] = mbuf[b * 32 + tid];
    sl[tid] = lbuf[b * 32 + tid];
  }
  __syncthreads();
  float M = -1e30f;
#pragma unroll
  for (int i = 0; i < 32; ++i) M = fmaxf(M, sm[i]);
  float D = 0.f;
#pragma unroll
  for (int i = 0; i < 32; ++i) D += __expf(sm[i] - M) * sl[i];
  const float inv = 1.f / D;
  const int f = tid * 2;
  float a0 = 0.f, a1 = 0.f;
  for (int i = 0; i < 32; ++i) {
    const float wi = __expf(sm[i] - M);
    const float2 v = *reinterpret_cast<const float2*>(
        &cpart[(size_t)(b * 32 + i) * 512 + f]);
    a0 += wi * v.x;
    a1 += wi * v.y;
  }
  c[b * FF + f]     = a0 * inv;
  c[b * FF + f + 1] = a1 * inv;
}

// --- gate GEMMs, LDS-tiled, split-K x8 ------------------------------------
__global__ __launch_bounds__(512) void k5a_gates(
    const float* __restrict__ x, const float* __restrict__ cc,
    const float* __restrict__ h, const float* __restrict__ kern,
    const float* __restrict__ ak, const float* __restrict__ rk,
    float* __restrict__ G) {
  __shared__ float wsx[64][64], wsa[64][64], wsr[64][64];
  __shared__ float xs[32][64], cs[32][64], hs[32][64];
  const int n0 = blockIdx.x * 64;
  const int kg0 = blockIdx.y * 64;
  const bool has_r = (n0 < 1024);
  const int tid = threadIdx.x;
  const int n = tid & 63;
  const int b0 = (tid >> 6) * 4;
  const int wrow = tid >> 3, wcol = (tid & 7) * 8;
  const int orow = tid >> 4, ocol = (tid & 15) * 4;
  float acc[4] = {0.f, 0.f, 0.f, 0.f};

  {
    const size_t wb = (size_t)(kg0 + wrow) * 1536 + n0 + wcol;
    *reinterpret_cast<float4*>(&wsx[wrow][wcol])     = *reinterpret_cast<const float4*>(kern + wb);
    *reinterpret_cast<float4*>(&wsx[wrow][wcol + 4]) = *reinterpret_cast<const float4*>(kern + wb + 4);
    *reinterpret_cast<float4*>(&wsa[wrow][wcol])     = *reinterpret_cast<const float4*>(ak + wb);
    *reinterpret_cast<float4*>(&wsa[wrow][wcol + 4]) = *reinterpret_cast<const float4*>(ak + wb + 4);
    if (has_r) {
      *reinterpret_cast<float4*>(&wsr[wrow][wcol])     = *reinterpret_cast<const float4*>(rk + wb);
      *reinterpret_cast<float4*>(&wsr[wrow][wcol + 4]) = *reinterpret_cast<const float4*>(rk + wb + 4);
    }
    *reinterpret_cast<float4*>(&xs[orow][ocol]) =
        *reinterpret_cast<const float4*>(x + orow * FF + kg0 + ocol);
    *reinterpret_cast<float4*>(&cs[orow][ocol]) =
        *reinterpret_cast<const float4*>(cc + orow * FF + kg0 + ocol);
    *reinterpret_cast<float4*>(&hs[orow][ocol]) =
        *reinterpret_cast<const float4*>(h + orow * UU + kg0 + ocol);
  }
  __syncthreads();
  if (has_r) {
#pragma unroll 8
    for (int k = 0; k < 64; ++k) {
      const float wx = wsx[k][n], wa = wsa[k][n], wr = wsr[k][n];
#pragma unroll
      for (int j = 0; j < 4; ++j)
        acc[j] += xs[b0 + j][k] * wx + cs[b0 + j][k] * wa + hs[b0 + j][k] * wr;
    }
  } else {
#pragma unroll 8
    for (int k = 0; k < 64; ++k) {
      const float wx = wsx[k][n], wa = wsa[k][n];
#pragma unroll
      for (int j = 0; j < 4; ++j)
        acc[j] += xs[b0 + j][k] * wx + cs[b0 + j][k] * wa;
    }
  }
#pragma unroll
  for (int j = 0; j < 4; ++j)
    atomicAdd(&G[(size_t)(b0 + j) * 1536 + n0 + n], acc[j]);
}

__global__ __launch_bounds__(256) void k5b_zr(
    const float* __restrict__ G, const float* __restrict__ h,
    const float* __restrict__ bias, const float* __restrict__ abias,
    float* __restrict__ zs, float* __restrict__ rh) {
  int idx = blockIdx.x * blockDim.x + threadIdx.x;  // 16384
  int b = idx >> 9;
  int u = idx & 511;
  float z = 0.2f * (G[(size_t)b * 1536 + u] + bias[u] + abias[u]) + 0.5f;
  z = fminf(fmaxf(z, 0.f), 1.f);
  float r = 0.2f * (G[(size_t)b * 1536 + 512 + u] + bias[512 + u] + abias[512 + u]) + 0.5f;
  r = fminf(fmaxf(r, 0.f), 1.f);
  zs[idx] = z;
  rh[idx] = r * h[idx];
}

__global__ __launch_bounds__(512) void k5c_q(
    const float* __restrict__ rh, const float* __restrict__ rk,
    float* __restrict__ qbuf) {
  __shared__ float wsr[64][64];
  __shared__ float rs[32][64];
  const int n0 = blockIdx.x * 64;
  const int kg0 = blockIdx.y * 64;
  const int tid = threadIdx.x;
  const int n = tid & 63;
  const int b0 = (tid >> 6) * 4;
  const int wrow = tid >> 3, wcol = (tid & 7) * 8;
  const int orow = tid >> 4, ocol = (tid & 15) * 4;
  float acc[4] = {0.f, 0.f, 0.f, 0.f};

  {
    const size_t wb = (size_t)(kg0 + wrow) * 1536 + 1024 + n0 + wcol;
    *reinterpret_cast<float4*>(&wsr[wrow][wcol])     = *reinterpret_cast<const float4*>(rk + wb);
    *reinterpret_cast<float4*>(&wsr[wrow][wcol + 4]) = *reinterpret_cast<const float4*>(rk + wb + 4);
    *reinterpret_cast<float4*>(&rs[orow][ocol]) =
        *reinterpret_cast<const float4*>(rh + orow * UU + kg0 + ocol);
  }
  __syncthreads();
#pragma unroll 8
  for (int k = 0; k < 64; ++k) {
    const float w = wsr[k][n];
#pragma unroll
    for (int j = 0; j < 4; ++j) acc[j] += rs[b0 + j][k] * w;
  }
#pragma unroll
  for (int j = 0; j < 4; ++j)
    atomicAdd(&qbuf[(b0 + j) * UU + n0 + n], acc[j]);
}

__global__ __launch_bounds__(256) void k5d_out(
    const float* __restrict__ G, const float* __restrict__ qbuf,
    const float* __restrict__ zs, const float* __restrict__ h,
    const float* __restrict__ bias, const float* __restrict__ abias,
    float* __restrict__ out) {
  int idx = blockIdx.x * blockDim.x + threadIdx.x;  // 16384
  int b = idx >> 9;
  int u = idx & 511;
  float hh = tanhf(G[(size_t)b * 1536 + 1024 + u] + bias[1024 + u] +
                   abias[1024 + u] + qbuf[idx]);
  float z = zs[idx];
  out[idx] = z * h[idx] + (1.f - z) * hh;
}

extern "C" void kernel_launch(void* const* d_in, const int* in_sizes, int n_in,
                              void* d_out, int out_size, void* d_ws, size_t ws_size,
                              hipStream_t stream) {
  const float* x       = (const float*)d_in[0];
  const float* h       = (const float*)d_in[1];
  const float* ann     = (const float*)d_in[2];
  const float* kern    = (const float*)d_in[3];
  const float* rk      = (const float*)d_in[4];
  const float* ak      = (const float*)d_in[5];
  const float* Wa      = (const float*)d_in[6];
  const float* Ua      = (const float*)d_in[7];
  const float* Va      = (const float*)d_in[8];
  const float* bias    = (const float*)d_in[9];
  const float* abias   = (const float*)d_in[10];
  const float* Wa_bias = (const float*)d_in[11];
  const float* Ua_bias = (const float*)d_in[12];

  float* ws     = (float*)d_ws;
  float* hw     = ws;            // 16384
  float* mbuf   = ws + 16384;    // 1024
  float* lbuf   = ws + 17408;    // 1024
  float* cpart  = ws + 18432;    // 524288
  float* c      = ws + 542720;   // 16384
  float* G      = ws + 559104;   // 49152
  float* qbuf   = ws + 608256;   // 16384
  float* zs     = ws + 624640;   // 16384
  float* rh     = ws + 641024;   // 16384
  short* Up     = (short*)(ws + 657408);  // 262144 shorts

  // zero atomic targets G + qbuf (contiguous 65536 floats)
  hipMemsetAsync(G, 0, 65536 * sizeof(float), stream);

  dim3 g0(32, 16);
  k0_pack<<<g0, 64, 0, stream>>>(Ua, Up);

  k1_hw<<<64, 256, 0, stream>>>(h, Wa, Wa_bias, Ua_bias, hw);

  dim3 g2(TT / 64, BB);
  k2_flash<<<g2, 1024, 0, stream>>>(ann, Up, Va, hw, mbuf, lbuf, cpart);

  k6_combine<<<BB, 256, 0, stream>>>(mbuf, lbuf, cpart, c);

  dim3 g5a(24, 8);
  k5a_gates<<<g5a, 512, 0, stream>>>(x, c, h, kern, ak, rk, G);

  k5b_zr<<<64, 256, 0, stream>>>(G, h, bias, abias, zs, rh);

  dim3 g5c(8, 8);
  k5c_q<<<g5c, 512, 0, stream>>>(rh, rk, qbuf);

  k5d_out<<<64, 256, 0, stream>>>(G, qbuf, zs, h, bias, abias, (float*)d_out);
}

// Round 9
// 104.387 us; speedup vs baseline: 1.1339x; 1.0544x over previous
//
#include <hip/hip_runtime.h>
#include <hip/hip_bf16.h>
#include <math.h>

#define BB 32
#define TT 2048
#define FF 512
#define UU 512

typedef __attribute__((ext_vector_type(4))) float f32x4;
typedef __attribute__((ext_vector_type(4))) short bf16x4;
typedef __attribute__((ext_vector_type(8))) short bf16x8;

__device__ inline short f2bf(float f) {
  union { __hip_bfloat16 h; short s; } u;
  u.h = __float2bfloat16(f);
  return u.s;
}

__device__ inline float bf2f(unsigned short s) {
  return __uint_as_float(((unsigned)s) << 16);
}

// tanh(x) = 1 - 2/(exp(2x)+1). ~6 VALU ops, ~1e-6 abs err, saturates right.
__device__ inline float tanh_fast(float x) {
  float e = __expf(2.0f * x);
  return 1.0f - 2.0f * __builtin_amdgcn_rcpf(e + 1.0f);
}

// ws layout (floats):
// hw:     [0,      16384)
// mbuf:   [16384,  16896)    32 b x 16 tiles
// lbuf:   [16896,  17408)
// cpart:  [17408,  279552)   32 b x 16 tiles x 512 f (f32)
// c:      [279552, 295936)   direct write by k6
// G:      [295936, 345088)   atomic target, zeroed up front
// qbuf:   [345088, 361472)   atomic target, zeroed up front
// zs:     [361472, 377856)
// rh:     [377856, 394240)
// Up:     shorts at float-offset 394240 (262144 shorts = 512 KB)

__global__ __launch_bounds__(256) void k1_hw(
    const float* __restrict__ h, const float* __restrict__ Wa,
    const float* __restrict__ Wa_bias, const float* __restrict__ Ua_bias,
    float* __restrict__ hw) {
  int idx = blockIdx.x * blockDim.x + threadIdx.x;  // 16384 = B*U
  int b = idx >> 9;
  int u = idx & 511;
  float acc = Wa_bias[u] + Ua_bias[u];
  const float* hrow = h + b * UU;
  for (int f = 0; f < FF; ++f) acc += hrow[f] * Wa[f * UU + u];
  hw[idx] = acc;
}

// Pack Ua (fp32 [k][n]) into fragment-native bf16 layout.
__global__ __launch_bounds__(64) void k0_pack(
    const float* __restrict__ Ua, short* __restrict__ Up) {
  const int n16 = blockIdx.x;   // 0..31
  const int k32 = blockIdx.y;   // 0..15
  const int l = threadIdx.x;    // 0..63
  const int n = n16 * 16 + (l & 15);
  const int g = l >> 4;
  bf16x8 v;
#pragma unroll
  for (int i = 0; i < 8; ++i) {
    int k = k32 * 32 + (i < 4 ? g * 4 + i : 16 + g * 4 + (i - 4));
    v[i] = f2bf(Ua[k * UU + n]);
  }
  *reinterpret_cast<bf16x8*>(Up + ((size_t)(n16 * 16 + k32) * 64 + l) * 8) = v;
}

// Flash kernel v5: t-tile = 128, 512 threads (8 waves), 1 block/CU.
// Wave w owns u-slice [64w, 64w+64): mf 0..7, nf 0..3. acc = 128 VGPR.
// Up traffic: 512 KB/block x 512 blocks = 256 MB; LDS A-reads halved vs v4.
__global__ __launch_bounds__(512, 2) void k2_flash(
    const float* __restrict__ ann, const short* __restrict__ Up,
    const float* __restrict__ Va, const float* __restrict__ hw,
    float* __restrict__ mbuf, float* __restrict__ lbuf,
    float* __restrict__ cpart) {
  __shared__ short Af[65536];      // 128 fb x 64 lane x 8 bf16 = 128 KB
  __shared__ float red[8][128];    // 4 KB
  __shared__ float e_all[128];
  __shared__ float sred[128];
  __shared__ float wtmp[4];
  __shared__ float ctxp[8][512];   // 16 KB
  const int tile = blockIdx.x;     // 0..15
  const int b = blockIdx.y;
  const int t0 = tile * 128;
  const int tid = threadIdx.x;     // 0..511
  const int w = tid >> 6;          // wave 0..7
  const int l = tid & 63;
  const int lo = l & 15;
  const int g = l >> 4;

  const float* annb = ann + ((size_t)b * TT + t0) * FF;

  // ---- stage: 8192 fragment entries (16 per thread). Per (v,wave): one fb
  // entry (16 rows x 128B), coalesced. fb = v*8 + w, slot = l. ----
#pragma unroll
  for (int v = 0; v < 16; ++v) {
    const int E = v * 512 + tid;
    const int fb = E >> 6;            // 0..127
    const int mfb = fb >> 4;
    const int k32 = fb & 15;
    const int row = mfb * 16 + lo;    // slot = l
    const float* src = annb + (size_t)row * FF + k32 * 32 + g * 4;
    f32x4 a0 = *reinterpret_cast<const f32x4*>(src);
    f32x4 a1 = *reinterpret_cast<const f32x4*>(src + 16);
    bf16x8 o;
    o[0] = f2bf(a0.x); o[1] = f2bf(a0.y); o[2] = f2bf(a0.z); o[3] = f2bf(a0.w);
    o[4] = f2bf(a1.x); o[5] = f2bf(a1.y); o[6] = f2bf(a1.z); o[7] = f2bf(a1.w);
    *reinterpret_cast<bf16x8*>(&Af[E * 8]) = o;
  }
  __syncthreads();

  // ---- MFMA: 8 mf x 4 nf, k32 = 0..15, 2-deep Up register prefetch ----
  f32x4 acc[8][4];
#pragma unroll
  for (int mf = 0; mf < 8; ++mf)
#pragma unroll
    for (int nf = 0; nf < 4; ++nf) acc[mf][nf] = (f32x4)0.f;

  const short* upb0 = Up + ((size_t)((w * 4 + 0) * 16) * 64 + l) * 8;
  const short* upb1 = Up + ((size_t)((w * 4 + 1) * 16) * 64 + l) * 8;
  const short* upb2 = Up + ((size_t)((w * 4 + 2) * 16) * 64 + l) * 8;
  const short* upb3 = Up + ((size_t)((w * 4 + 3) * 16) * 64 + l) * 8;

  bf16x8 pA[4], pB[4];
  pA[0] = *reinterpret_cast<const bf16x8*>(upb0);
  pA[1] = *reinterpret_cast<const bf16x8*>(upb1);
  pA[2] = *reinterpret_cast<const bf16x8*>(upb2);
  pA[3] = *reinterpret_cast<const bf16x8*>(upb3);
  pB[0] = *reinterpret_cast<const bf16x8*>(upb0 + 512);
  pB[1] = *reinterpret_cast<const bf16x8*>(upb1 + 512);
  pB[2] = *reinterpret_cast<const bf16x8*>(upb2 + 512);
  pB[3] = *reinterpret_cast<const bf16x8*>(upb3 + 512);

#pragma unroll
  for (int kk = 0; kk < 8; ++kk) {
    const int k0 = 2 * kk;
    __builtin_amdgcn_s_setprio(1);
#pragma unroll
    for (int mf = 0; mf < 8; ++mf) {
      bf16x8 af = *reinterpret_cast<const bf16x8*>(
          &Af[((mf * 16 + k0) * 64 + l) * 8]);
#pragma unroll
      for (int nf = 0; nf < 4; ++nf)
        acc[mf][nf] = __builtin_amdgcn_mfma_f32_16x16x32_bf16(
            af, pA[nf], acc[mf][nf], 0, 0, 0);
    }
    __builtin_amdgcn_s_setprio(0);
    if (kk < 7) {
      pA[0] = *reinterpret_cast<const bf16x8*>(upb0 + (k0 + 2) * 512);
      pA[1] = *reinterpret_cast<const bf16x8*>(upb1 + (k0 + 2) * 512);
      pA[2] = *reinterpret_cast<const bf16x8*>(upb2 + (k0 + 2) * 512);
      pA[3] = *reinterpret_cast<const bf16x8*>(upb3 + (k0 + 2) * 512);
    }
    __builtin_amdgcn_s_setprio(1);
#pragma unroll
    for (int mf = 0; mf < 8; ++mf) {
      bf16x8 af = *reinterpret_cast<const bf16x8*>(
          &Af[((mf * 16 + k0 + 1) * 64 + l) * 8]);
#pragma unroll
      for (int nf = 0; nf < 4; ++nf)
        acc[mf][nf] = __builtin_amdgcn_mfma_f32_16x16x32_bf16(
            af, pB[nf], acc[mf][nf], 0, 0, 0);
    }
    __builtin_amdgcn_s_setprio(0);
    if (kk < 7) {
      pB[0] = *reinterpret_cast<const bf16x8*>(upb0 + (k0 + 3) * 512);
      pB[1] = *reinterpret_cast<const bf16x8*>(upb1 + (k0 + 3) * 512);
      pB[2] = *reinterpret_cast<const bf16x8*>(upb2 + (k0 + 3) * 512);
      pB[3] = *reinterpret_cast<const bf16x8*>(upb3 + (k0 + 3) * 512);
    }
  }

  // ---- scores epilogue: tanh(acc + hw[u]) * Va[u], reduce over u ----
  const float* hwb = hw + b * UU;
  float part[8][4];
#pragma unroll
  for (int mf = 0; mf < 8; ++mf)
#pragma unroll
    for (int r = 0; r < 4; ++r) part[mf][r] = 0.f;
#pragma unroll
  for (int nf = 0; nf < 4; ++nf) {
    const int u = w * 64 + nf * 16 + lo;
    const float hv = hwb[u];
    const float vv = Va[u];
#pragma unroll
    for (int mf = 0; mf < 8; ++mf)
#pragma unroll
      for (int r = 0; r < 4; ++r)
        part[mf][r] += tanh_fast(acc[mf][nf][r] + hv) * vv;
  }
#pragma unroll
  for (int mf = 0; mf < 8; ++mf)
#pragma unroll
    for (int r = 0; r < 4; ++r) {
      float s = part[mf][r];
      s += __shfl_xor(s, 1);
      s += __shfl_xor(s, 2);
      s += __shfl_xor(s, 4);
      s += __shfl_xor(s, 8);
      part[mf][r] = s;
    }
  if (lo == 0) {
#pragma unroll
    for (int mf = 0; mf < 8; ++mf)
#pragma unroll
      for (int r = 0; r < 4; ++r)
        red[w][mf * 16 + g * 4 + r] = part[mf][r];
  }
  __syncthreads();

  // ---- tile softmax stats over 128 rows (2 waves) ----
  if (tid < 128) {
    float s = red[0][tid] + red[1][tid] + red[2][tid] + red[3][tid] +
              red[4][tid] + red[5][tid] + red[6][tid] + red[7][tid];
    sred[tid] = s;
    float m = s;
#pragma unroll
    for (int off = 1; off < 64; off <<= 1) m = fmaxf(m, __shfl_xor(m, off));
    if ((tid & 63) == 0) wtmp[tid >> 6] = m;
  }
  __syncthreads();
  if (tid < 128) {
    float m = fmaxf(wtmp[0], wtmp[1]);
    float e = __expf(sred[tid] - m);
    e_all[tid] = e;
    float ls = e;
#pragma unroll
    for (int off = 1; off < 64; off <<= 1) ls += __shfl_xor(ls, off);
    if ((tid & 63) == 0) wtmp[2 + (tid >> 6)] = ls;
    if (tid == 0) mbuf[b * 16 + tile] = m;
  }
  __syncthreads();
  if (tid == 0) lbuf[b * 16 + tile] = wtmp[2] + wtmp[3];

  // ---- partial context, vectorized: 64 f-owners x 8 t-slices ----
  {
    const int fo = tid & 63;         // kk2 = fo>>2, gg = fo&3
    const int ts = tid >> 6;         // t-slice: t in [ts*16, ts*16+16)
    const int kk2 = fo >> 2;
    const int gg = fo & 3;
    float a8[8];
#pragma unroll
    for (int j = 0; j < 8; ++j) a8[j] = 0.f;
#pragma unroll
    for (int it = 0; it < 16; ++it) {
      const int tl = (it + fo) & 15;           // stagger vs bank collisions
      const int t = ts * 16 + tl;
      const int entry = (ts * 16 + kk2) * 64 + gg * 16 + tl;
      bf16x8 v = *reinterpret_cast<const bf16x8*>(&Af[entry * 8]);
      const float e = e_all[t];
#pragma unroll
      for (int j = 0; j < 8; ++j)
        a8[j] += e * bf2f((unsigned short)v[j]);
    }
#pragma unroll
    for (int j = 0; j < 8; ++j) ctxp[ts][fo * 8 + j] = a8[j];
  }
  __syncthreads();
  {
    float s = 0.f;
#pragma unroll
    for (int ts2 = 0; ts2 < 8; ++ts2) s += ctxp[ts2][tid];
    const int fo2 = tid >> 3;
    const int j2 = tid & 7;
    const int f = (fo2 >> 2) * 32 +
                  ((j2 < 4) ? (fo2 & 3) * 4 + j2 : 16 + (fo2 & 3) * 4 + (j2 - 4));
    cpart[(size_t)(b * 16 + tile) * 512 + f] = s;
  }
}

// Combine tile partials: c[b][f] = sum_i w_i*cpart_i[f] / sum_i w_i*l_i.
__global__ __launch_bounds__(256) void k6_combine(
    const float* __restrict__ mbuf, const float* __restrict__ lbuf,
    const float* __restrict__ cpart, float* __restrict__ c) {
  const int b = blockIdx.x;
  const int tid = threadIdx.x;
  __shared__ float sm[16], sl[16];
  if (tid < 16) {
    sm[tid] = mbuf[b * 16 + tid];
    sl[tid] = lbuf[b * 16 + tid];
  }
  __syncthreads();
  float M = -1e30f;
#pragma unroll
  for (int i = 0; i < 16; ++i) M = fmaxf(M, sm[i]);
  float D = 0.f;
#pragma unroll
  for (int i = 0; i < 16; ++i) D += __expf(sm[i] - M) * sl[i];
  const float inv = 1.f / D;
  const int f = tid * 2;
  float a0 = 0.f, a1 = 0.f;
#pragma unroll
  for (int i = 0; i < 16; ++i) {
    const float wi = __expf(sm[i] - M);
    const float2 v = *reinterpret_cast<const float2*>(
        &cpart[(size_t)(b * 16 + i) * 512 + f]);
    a0 += wi * v.x;
    a1 += wi * v.y;
  }
  c[b * FF + f]     = a0 * inv;
  c[b * FF + f + 1] = a1 * inv;
}

// --- gate GEMMs, LDS-tiled, split-K x8 ------------------------------------
__global__ __launch_bounds__(512) void k5a_gates(
    const float* __restrict__ x, const float* __restrict__ cc,
    const float* __restrict__ h, const float* __restrict__ kern,
    const float* __restrict__ ak, const float* __restrict__ rk,
    float* __restrict__ G) {
  __shared__ float wsx[64][64], wsa[64][64], wsr[64][64];
  __shared__ float xs[32][64], cs[32][64], hs[32][64];
  const int n0 = blockIdx.x * 64;
  const int kg0 = blockIdx.y * 64;
  const bool has_r = (n0 < 1024);
  const int tid = threadIdx.x;
  const int n = tid & 63;
  const int b0 = (tid >> 6) * 4;
  const int wrow = tid >> 3, wcol = (tid & 7) * 8;
  const int orow = tid >> 4, ocol = (tid & 15) * 4;
  float acc[4] = {0.f, 0.f, 0.f, 0.f};

  {
    const size_t wb = (size_t)(kg0 + wrow) * 1536 + n0 + wcol;
    *reinterpret_cast<float4*>(&wsx[wrow][wcol])     = *reinterpret_cast<const float4*>(kern + wb);
    *reinterpret_cast<float4*>(&wsx[wrow][wcol + 4]) = *reinterpret_cast<const float4*>(kern + wb + 4);
    *reinterpret_cast<float4*>(&wsa[wrow][wcol])     = *reinterpret_cast<const float4*>(ak + wb);
    *reinterpret_cast<float4*>(&wsa[wrow][wcol + 4]) = *reinterpret_cast<const float4*>(ak + wb + 4);
    if (has_r) {
      *reinterpret_cast<float4*>(&wsr[wrow][wcol])     = *reinterpret_cast<const float4*>(rk + wb);
      *reinterpret_cast<float4*>(&wsr[wrow][wcol + 4]) = *reinterpret_cast<const float4*>(rk + wb + 4);
    }
    *reinterpret_cast<float4*>(&xs[orow][ocol]) =
        *reinterpret_cast<const float4*>(x + orow * FF + kg0 + ocol);
    *reinterpret_cast<float4*>(&cs[orow][ocol]) =
        *reinterpret_cast<const float4*>(cc + orow * FF + kg0 + ocol);
    *reinterpret_cast<float4*>(&hs[orow][ocol]) =
        *reinterpret_cast<const float4*>(h + orow * UU + kg0 + ocol);
  }
  __syncthreads();
  if (has_r) {
#pragma unroll 8
    for (int k = 0; k < 64; ++k) {
      const float wx = wsx[k][n], wa = wsa[k][n], wr = wsr[k][n];
#pragma unroll
      for (int j = 0; j < 4; ++j)
        acc[j] += xs[b0 + j][k] * wx + cs[b0 + j][k] * wa + hs[b0 + j][k] * wr;
    }
  } else {
#pragma unroll 8
    for (int k = 0; k < 64; ++k) {
      const float wx = wsx[k][n], wa = wsa[k][n];
#pragma unroll
      for (int j = 0; j < 4; ++j)
        acc[j] += xs[b0 + j][k] * wx + cs[b0 + j][k] * wa;
    }
  }
#pragma unroll
  for (int j = 0; j < 4; ++j)
    atomicAdd(&G[(size_t)(b0 + j) * 1536 + n0 + n], acc[j]);
}

__global__ __launch_bounds__(256) void k5b_zr(
    const float* __restrict__ G, const float* __restrict__ h,
    const float* __restrict__ bias, const float* __restrict__ abias,
    float* __restrict__ zs, float* __restrict__ rh) {
  int idx = blockIdx.x * blockDim.x + threadIdx.x;  // 16384
  int b = idx >> 9;
  int u = idx & 511;
  float z = 0.2f * (G[(size_t)b * 1536 + u] + bias[u] + abias[u]) + 0.5f;
  z = fminf(fmaxf(z, 0.f), 1.f);
  float r = 0.2f * (G[(size_t)b * 1536 + 512 + u] + bias[512 + u] + abias[512 + u]) + 0.5f;
  r = fminf(fmaxf(r, 0.f), 1.f);
  zs[idx] = z;
  rh[idx] = r * h[idx];
}

__global__ __launch_bounds__(512) void k5c_q(
    const float* __restrict__ rh, const float* __restrict__ rk,
    float* __restrict__ qbuf) {
  __shared__ float wsr[64][64];
  __shared__ float rs[32][64];
  const int n0 = blockIdx.x * 64;
  const int kg0 = blockIdx.y * 64;
  const int tid = threadIdx.x;
  const int n = tid & 63;
  const int b0 = (tid >> 6) * 4;
  const int wrow = tid >> 3, wcol = (tid & 7) * 8;
  const int orow = tid >> 4, ocol = (tid & 15) * 4;
  float acc[4] = {0.f, 0.f, 0.f, 0.f};

  {
    const size_t wb = (size_t)(kg0 + wrow) * 1536 + 1024 + n0 + wcol;
    *reinterpret_cast<float4*>(&wsr[wrow][wcol])     = *reinterpret_cast<const float4*>(rk + wb);
    *reinterpret_cast<float4*>(&wsr[wrow][wcol + 4]) = *reinterpret_cast<const float4*>(rk + wb + 4);
    *reinterpret_cast<float4*>(&rs[orow][ocol]) =
        *reinterpret_cast<const float4*>(rh + orow * UU + kg0 + ocol);
  }
  __syncthreads();
#pragma unroll 8
  for (int k = 0; k < 64; ++k) {
    const float w = wsr[k][n];
#pragma unroll
    for (int j = 0; j < 4; ++j) acc[j] += rs[b0 + j][k] * w;
  }
#pragma unroll
  for (int j = 0; j < 4; ++j)
    atomicAdd(&qbuf[(b0 + j) * UU + n0 + n], acc[j]);
}

__global__ __launch_bounds__(256) void k5d_out(
    const float* __restrict__ G, const float* __restrict__ qbuf,
    const float* __restrict__ zs, const float* __restrict__ h,
    const float* __restrict__ bias, const float* __restrict__ abias,
    float* __restrict__ out) {
  int idx = blockIdx.x * blockDim.x + threadIdx.x;  // 16384
  int b = idx >> 9;
  int u = idx & 511;
  float hh = tanhf(G[(size_t)b * 1536 + 1024 + u] + bias[1024 + u] +
                   abias[1024 + u] + qbuf[idx]);
  float z = zs[idx];
  out[idx] = z * h[idx] + (1.f - z) * hh;
}

extern "C" void kernel_launch(void* const* d_in, const int* in_sizes, int n_in,
                              void* d_out, int out_size, void* d_ws, size_t ws_size,
                              hipStream_t stream) {
  const float* x       = (const float*)d_in[0];
  const float* h       = (const float*)d_in[1];
  const float* ann     = (const float*)d_in[2];
  const float* kern    = (const float*)d_in[3];
  const float* rk      = (const float*)d_in[4];
  const float* ak      = (const float*)d_in[5];
  const float* Wa      = (const float*)d_in[6];
  const float* Ua      = (const float*)d_in[7];
  const float* Va      = (const float*)d_in[8];
  const float* bias    = (const float*)d_in[9];
  const float* abias   = (const float*)d_in[10];
  const float* Wa_bias = (const float*)d_in[11];
  const float* Ua_bias = (const float*)d_in[12];

  float* ws     = (float*)d_ws;
  float* hw     = ws;            // 16384
  float* mbuf   = ws + 16384;    // 512
  float* lbuf   = ws + 16896;    // 512
  float* cpart  = ws + 17408;    // 262144
  float* c      = ws + 279552;   // 16384
  float* G      = ws + 295936;   // 49152
  float* qbuf   = ws + 345088;   // 16384
  float* zs     = ws + 361472;   // 16384
  float* rh     = ws + 377856;   // 16384
  short* Up     = (short*)(ws + 394240);  // 262144 shorts

  // zero atomic targets G + qbuf (contiguous 65536 floats)
  hipMemsetAsync(G, 0, 65536 * sizeof(float), stream);

  dim3 g0(32, 16);
  k0_pack<<<g0, 64, 0, stream>>>(Ua, Up);

  k1_hw<<<64, 256, 0, stream>>>(h, Wa, Wa_bias, Ua_bias, hw);

  dim3 g2(TT / 128, BB);
  k2_flash<<<g2, 512, 0, stream>>>(ann, Up, Va, hw, mbuf, lbuf, cpart);

  k6_combine<<<BB, 256, 0, stream>>>(mbuf, lbuf, cpart, c);

  dim3 g5a(24, 8);
  k5a_gates<<<g5a, 512, 0, stream>>>(x, c, h, kern, ak, rk, G);

  k5b_zr<<<64, 256, 0, stream>>>(G, h, bias, abias, zs, rh);

  dim3 g5c(8, 8);
  k5c_q<<<g5c, 512, 0, stream>>>(rh, rk, qbuf);

  k5d_out<<<64, 256, 0, stream>>>(G, qbuf, zs, h, bias, abias, (float*)d_out);
}